// Round 2
// baseline (24861.444 us; speedup 1.0000x reference)
//
#include <hip/hip_runtime.h>

#define BB 65536
#define TT 12
#define HD 128
#define G3 384
#define LL 3
#define NCH 4
#define BC (BB / NCH)            // 16384 rows per chunk

// ---------------------------------------------------------------------------
// Embedding: xout[b,e] = relu(x_true[b,t,0]*Wemb[e,0] + x_true[b,t,1]*Wemb[e,1] + bemb[e])
// (pointers pre-offset to the chunk; b is chunk-local)
// ---------------------------------------------------------------------------
__global__ __launch_bounds__(256) void embed_kernel(
    const float* __restrict__ x_true, const float* __restrict__ Wemb,
    const float* __restrict__ bemb, float* __restrict__ xout, int t) {
  int idx = blockIdx.x * 256 + threadIdx.x;
  int b = idx >> 7, e = idx & 127;
  float w0 = Wemb[e * 2 + 0];
  float w1 = Wemb[e * 2 + 1];
  float x0 = x_true[(b * TT + t) * 2 + 0];
  float x1 = x_true[(b * TT + t) * 2 + 1];
  float v = x0 * w0 + x1 * w1 + bemb[e];
  xout[idx] = v > 0.f ? v : 0.f;
}

// ---------------------------------------------------------------------------
// Fused GRU cell: hnew = GRUCell(xin, hold), PyTorch gate order (r,z,n).
// Block: 256 thr = 16 units (tx) x 16 row-groups (ty); 8 rows/thread.
// Grid: (BC/128, 128/16). Weight triples for this block's 16 units in LDS.
// ---------------------------------------------------------------------------
__global__ __launch_bounds__(256) void gru_cell_kernel(
    const float* __restrict__ xin, const float* __restrict__ hold,
    float* __restrict__ hnew,
    const float* __restrict__ Wih, const float* __restrict__ Whh,
    const float* __restrict__ bih, const float* __restrict__ bhh) {
  __shared__ float Wi[3][16][132];   // [gate][unit][k], pad 132 (row = 528B, 16B-aligned)
  __shared__ float Wh[3][16][132];
  __shared__ float bi[3][16];
  __shared__ float bh[3][16];

  const int tid = threadIdx.x;
  const int u0 = blockIdx.y * 16;

  for (int i = tid; i < 3 * 16 * 128; i += 256) {
    int g = i >> 11, j = (i >> 7) & 15, k = i & 127;
    Wi[g][j][k] = Wih[(g * 128 + u0 + j) * 128 + k];
    Wh[g][j][k] = Whh[(g * 128 + u0 + j) * 128 + k];
  }
  if (tid < 48) {
    bi[tid >> 4][tid & 15] = bih[(tid >> 4) * 128 + u0 + (tid & 15)];
  } else if (tid < 96) {
    int t2 = tid - 48;
    bh[t2 >> 4][t2 & 15] = bhh[(t2 >> 4) * 128 + u0 + (t2 & 15)];
  }
  __syncthreads();

  const int tx = tid & 15, ty = tid >> 4;
  const int m0 = blockIdx.x * 128 + ty * 8;

  const float4* __restrict__ xin4  = reinterpret_cast<const float4*>(xin);
  const float4* __restrict__ hold4 = reinterpret_cast<const float4*>(hold);
  const float4* __restrict__ wir = reinterpret_cast<const float4*>(&Wi[0][tx][0]);
  const float4* __restrict__ wiz = reinterpret_cast<const float4*>(&Wi[1][tx][0]);
  const float4* __restrict__ win = reinterpret_cast<const float4*>(&Wi[2][tx][0]);
  const float4* __restrict__ whr = reinterpret_cast<const float4*>(&Wh[0][tx][0]);
  const float4* __restrict__ whz = reinterpret_cast<const float4*>(&Wh[1][tx][0]);
  const float4* __restrict__ whn = reinterpret_cast<const float4*>(&Wh[2][tx][0]);

  float ax0[8] = {}, ax1[8] = {}, ax2[8] = {};
  float ah0[8] = {}, ah1[8] = {}, ah2[8] = {};

  for (int k4 = 0; k4 < 32; ++k4) {
    float4 a = wir[k4], bq = wiz[k4], c = win[k4];
    float4 d = whr[k4], e  = whz[k4], f = whn[k4];
#pragma unroll
    for (int rr = 0; rr < 8; ++rr) {
      float4 xv = xin4[(m0 + rr) * 32 + k4];
      float4 hv = hold4[(m0 + rr) * 32 + k4];
      ax0[rr] += xv.x * a.x + xv.y * a.y + xv.z * a.z + xv.w * a.w;
      ax1[rr] += xv.x * bq.x + xv.y * bq.y + xv.z * bq.z + xv.w * bq.w;
      ax2[rr] += xv.x * c.x + xv.y * c.y + xv.z * c.z + xv.w * c.w;
      ah0[rr] += hv.x * d.x + hv.y * d.y + hv.z * d.z + hv.w * d.w;
      ah1[rr] += hv.x * e.x + hv.y * e.y + hv.z * e.z + hv.w * e.w;
      ah2[rr] += hv.x * f.x + hv.y * f.y + hv.z * f.z + hv.w * f.w;
    }
  }

#pragma unroll
  for (int rr = 0; rr < 8; ++rr) {
    int m = m0 + rr;
    float r = 1.f / (1.f + expf(-(ax0[rr] + ah0[rr] + bi[0][tx] + bh[0][tx])));
    float z = 1.f / (1.f + expf(-(ax1[rr] + ah1[rr] + bi[1][tx] + bh[1][tx])));
    float n = tanhf(ax2[rr] + bi[2][tx] + r * (ah2[rr] + bh[2][tx]));
    float hp = hold[m * 128 + u0 + tx];
    hnew[m * 128 + u0 + tx] = (1.f - z) * n + z * hp;
  }
}

// ---------------------------------------------------------------------------
// Linear: out = act(xin @ W^T + b), W [128,128]. Same tiling as the cell.
// ---------------------------------------------------------------------------
template <int RELU>
__global__ __launch_bounds__(256) void linear_kernel(
    const float* __restrict__ xin, const float* __restrict__ W,
    const float* __restrict__ bias, float* __restrict__ out) {
  __shared__ float Wl[16][132];
  __shared__ float bl[16];
  const int tid = threadIdx.x;
  const int u0 = blockIdx.y * 16;
  for (int i = tid; i < 2048; i += 256) {
    Wl[i >> 7][i & 127] = W[(u0 + (i >> 7)) * 128 + (i & 127)];
  }
  if (tid < 16) bl[tid] = bias[u0 + tid];
  __syncthreads();

  const int tx = tid & 15, ty = tid >> 4;
  const int m0 = blockIdx.x * 128 + ty * 8;
  const float4* __restrict__ xin4 = reinterpret_cast<const float4*>(xin);
  const float4* __restrict__ wp = reinterpret_cast<const float4*>(&Wl[tx][0]);

  float acc[8] = {};
  for (int k4 = 0; k4 < 32; ++k4) {
    float4 w = wp[k4];
#pragma unroll
    for (int rr = 0; rr < 8; ++rr) {
      float4 xv = xin4[(m0 + rr) * 32 + k4];
      acc[rr] += xv.x * w.x + xv.y * w.y + xv.z * w.z + xv.w * w.w;
    }
  }
#pragma unroll
  for (int rr = 0; rr < 8; ++rr) {
    float v = acc[rr] + bl[tx];
    if (RELU) v = v > 0.f ? v : 0.f;
    out[(m0 + rr) * 128 + u0 + tx] = v;
  }
}

// ---------------------------------------------------------------------------
// Output projection: y[b,t,0:2] = htop[b,:] @ Wout^T + bout. 4 lanes per row.
// ---------------------------------------------------------------------------
__global__ __launch_bounds__(256) void y_kernel(
    const float* __restrict__ htop, const float* __restrict__ Wout,
    const float* __restrict__ bout, float* __restrict__ out, int t) {
  __shared__ float wl[2][128];
  __shared__ float blv[2];
  const int tid = threadIdx.x;
  wl[tid >> 7][tid & 127] = Wout[tid];
  if (tid < 2) blv[tid] = bout[tid];
  __syncthreads();

  const int q = tid & 3, r4 = tid >> 2;
  const int b = blockIdx.x * 64 + r4;
  const float4* __restrict__ h4 = reinterpret_cast<const float4*>(htop);
  const float4* __restrict__ w0p = reinterpret_cast<const float4*>(&wl[0][0]);
  const float4* __restrict__ w1p = reinterpret_cast<const float4*>(&wl[1][0]);

  float s0 = 0.f, s1 = 0.f;
#pragma unroll
  for (int i = 0; i < 8; ++i) {
    int k4 = q + i * 4;
    float4 hv = h4[b * 32 + k4];
    float4 w0 = w0p[k4];
    float4 w1 = w1p[k4];
    s0 += hv.x * w0.x + hv.y * w0.y + hv.z * w0.z + hv.w * w0.w;
    s1 += hv.x * w1.x + hv.y * w1.y + hv.z * w1.z + hv.w * w1.w;
  }
  s0 += __shfl_xor(s0, 1); s0 += __shfl_xor(s0, 2);
  s1 += __shfl_xor(s1, 1); s1 += __shfl_xor(s1, 2);
  if (q == 0) {
    float2 v;
    v.x = s0 + blv[0];
    v.y = s1 + blv[1];
    *reinterpret_cast<float2*>(&out[b * (TT * 2) + t * 2]) = v;
  }
}

// ---------------------------------------------------------------------------
extern "C" void kernel_launch(void* const* d_in, const int* in_sizes, int n_in,
                              void* d_out, int out_size, void* d_ws, size_t ws_size,
                              hipStream_t stream) {
  const float* x_true   = (const float*)d_in[0];
  const float* enc_Wemb = (const float*)d_in[1];
  const float* enc_bemb = (const float*)d_in[2];
  const float* enc_Wih  = (const float*)d_in[3];
  const float* enc_Whh  = (const float*)d_in[4];
  const float* enc_bih  = (const float*)d_in[5];
  const float* enc_bhh  = (const float*)d_in[6];
  const float* enc_Wt   = (const float*)d_in[7];
  const float* enc_bt   = (const float*)d_in[8];
  const float* dec_Win  = (const float*)d_in[9];
  const float* dec_bin  = (const float*)d_in[10];
  const float* dec_Wih  = (const float*)d_in[11];
  const float* dec_Whh  = (const float*)d_in[12];
  const float* dec_bih  = (const float*)d_in[13];
  const float* dec_bhh  = (const float*)d_in[14];
  const float* dec_Wout = (const float*)d_in[15];
  const float* dec_bout = (const float*)d_in[16];
  float* out = (float*)d_out;

  float* ws = (float*)d_ws;
  const size_t NBHc = (size_t)BC * HD;       // 2,097,152 floats per buffer
  // Workspace: 4 rotation buffers + 1 shared x/rin buffer = 5 * 8.39 MB = 41.9 MB
  float* P[4] = {ws, ws + NBHc, ws + 2 * NBHc, ws + 3 * NBHc};
  float* X = ws + 4 * NBHc;

  dim3 blk(256);
  dim3 gcell(BC / 128, 8);
  dim3 gemb(BC * HD / 256);
  dim3 gy(BC / 64);

  for (int c = 0; c < NCH; ++c) {
    const float* xt_c = x_true + (size_t)c * BC * TT * 2;
    float*       out_c = out + (size_t)c * BC * TT * 2;

    // ---------------- Encoder ----------------
    hipMemsetAsync(P[0], 0, 3 * NBHc * sizeof(float), stream);  // P[0..2] contiguous
    int slot[3] = {0, 1, 2};
    int freeS = 3;
    for (int t = 1; t <= TT - 2; ++t) {       // x[:, 1:T-1] -> t = 1..10
      embed_kernel<<<gemb, blk, 0, stream>>>(xt_c, enc_Wemb, enc_bemb, X, t);
      const float* inp = X;
      for (int l = 0; l < LL; ++l) {
        gru_cell_kernel<<<gcell, blk, 0, stream>>>(
            inp, P[slot[l]], P[freeS],
            enc_Wih + (size_t)l * G3 * HD, enc_Whh + (size_t)l * G3 * HD,
            enc_bih + l * G3, enc_bhh + l * G3);
        int old = slot[l]; slot[l] = freeS; freeS = old;
        inp = P[slot[l]];
      }
    }
    // rep = alpha @ Wt^T + bt  -> goes into the current free slot
    linear_kernel<0><<<gcell, blk, 0, stream>>>(P[slot[2]], enc_Wt, enc_bt, P[freeS]);
    int repSlot = freeS;

    // ---------------- Decoder ----------------
    // zero the 3 non-rep slots (stale encoder hidden)
    for (int l = 0; l < LL; ++l)
      hipMemsetAsync(P[slot[l]], 0, NBHc * sizeof(float), stream);
    const float* carry = P[repSlot];
    int freeD = repSlot;                       // rep slot is overwritten after consumption
    for (int s = 0; s < TT; ++s) {
      linear_kernel<1><<<gcell, blk, 0, stream>>>(carry, dec_Win, dec_bin, X);
      const float* inp = X;
      for (int l = 0; l < LL; ++l) {
        gru_cell_kernel<<<gcell, blk, 0, stream>>>(
            inp, P[slot[l]], P[freeD],
            dec_Wih + (size_t)l * G3 * HD, dec_Whh + (size_t)l * G3 * HD,
            dec_bih + l * G3, dec_bhh + l * G3);
        int old = slot[l]; slot[l] = freeD; freeD = old;
        inp = P[slot[l]];
      }
      y_kernel<<<gy, blk, 0, stream>>>(P[slot[2]], dec_Wout, dec_bout, out_c, s);
      carry = P[slot[2]];
    }
  }
}

// Round 3
// 6733.543 us; speedup vs baseline: 3.6922x; 3.6922x over previous
//
#include <hip/hip_runtime.h>
#include <hip/hip_bf16.h>

#define TT 12
#define HD 128
#define G3 384
#define LL 3

typedef short bf16x8 __attribute__((ext_vector_type(8)));
typedef float f32x4 __attribute__((ext_vector_type(4)));
typedef unsigned short u16;

__device__ __forceinline__ float b2f(u16 u) {
  union { unsigned int i; float f; } c; c.i = ((unsigned int)u) << 16; return c.f;
}
__device__ __forceinline__ u16 f2b(float f) {
  __hip_bfloat16 h = __float2bfloat16(f);
  union { __hip_bfloat16 h; u16 u; } c; c.h = h; return c.u;
}
__device__ __forceinline__ float sigm(float x) { return 1.f / (1.f + expf(-x)); }

// ---------------------------------------------------------------------------
__global__ __launch_bounds__(256) void cvt_kernel(const float* __restrict__ s,
                                                  u16* __restrict__ d, int n) {
  int i = blockIdx.x * 256 + threadIdx.x;
  if (i < n) d[i] = f2b(s[i]);
}

// ---------------------------------------------------------------------------
// Embedding -> split bf16 (hi/lo). One thread = 8 consecutive emb elements.
// ---------------------------------------------------------------------------
__global__ __launch_bounds__(256) void embed_kernel(
    const float* __restrict__ x_true, const float* __restrict__ Wemb,
    const float* __restrict__ bemb, u16* __restrict__ xhi,
    u16* __restrict__ xlo, int t) {
  int idx = blockIdx.x * 256 + threadIdx.x;
  int b = idx >> 4, k0 = (idx & 15) * 8;
  float x0 = x_true[(b * TT + t) * 2 + 0];
  float x1 = x_true[(b * TT + t) * 2 + 1];
  bf16x8 vh, vl;
#pragma unroll
  for (int j = 0; j < 8; ++j) {
    int e = k0 + j;
    float v = x0 * Wemb[e * 2] + x1 * Wemb[e * 2 + 1] + bemb[e];
    v = v > 0.f ? v : 0.f;
    u16 hb = f2b(v);
    vh[j] = (short)hb;
    vl[j] = (short)f2b(v - b2f(hb));
  }
  *reinterpret_cast<bf16x8*>(xhi + b * 128 + k0) = vh;
  *reinterpret_cast<bf16x8*>(xlo + b * 128 + k0) = vl;
}

// ---------------------------------------------------------------------------
// MFMA GRU cell, split-A. Block=4 waves; wave w -> units u0=by*64+w*16.
// Wave processes 4 M-tiles of 16 rows (block = 64 rows). No LDS.
// A-frag: 8 consecutive bf16 of activation row (lane&15), k-group lane>>4.
// B-frag: 8 consecutive k of weight row u (lane&15).
// C/D: col=lane&15 (unit), row=(lane>>4)*4+reg.
// ---------------------------------------------------------------------------
__global__ __launch_bounds__(256) void gru_cell_mfma(
    const u16* __restrict__ xhi, const u16* __restrict__ xlo,
    const u16* __restrict__ hhi, const u16* __restrict__ hlo,
    u16* __restrict__ ohi, u16* __restrict__ olo,
    const u16* __restrict__ Wi, const u16* __restrict__ Wh,  // [384][128] bf16
    const float* __restrict__ bih, const float* __restrict__ bhh) {
  const int lane = threadIdx.x & 63;
  const int wv = threadIdx.x >> 6;
  const int col = lane & 15;
  const int kg = lane >> 4;
  const int u = blockIdx.y * 64 + wv * 16 + col;
  const int r0b = blockIdx.x * 64;

  bf16x8 wfi[3][4], wfh[3][4];
#pragma unroll
  for (int g = 0; g < 3; ++g)
#pragma unroll
    for (int kf = 0; kf < 4; ++kf) {
      int off = (g * 128 + u) * 128 + kf * 32 + kg * 8;
      wfi[g][kf] = *reinterpret_cast<const bf16x8*>(Wi + off);
      wfh[g][kf] = *reinterpret_cast<const bf16x8*>(Wh + off);
    }

  const float br_i = bih[u], bz_i = bih[128 + u], bn_i = bih[256 + u];
  const float br_h = bhh[u], bz_h = bhh[128 + u], bn_h = bhh[256 + u];
  const f32x4 zz = {0.f, 0.f, 0.f, 0.f};

#pragma unroll
  for (int mt = 0; mt < 4; ++mt) {
    const int r0 = r0b + mt * 16;
    const int abase = (r0 + col) * 128 + kg * 8;
    f32x4 ax[3] = {zz, zz, zz}, ah[3] = {zz, zz, zz};
#pragma unroll
    for (int kf = 0; kf < 4; ++kf) {
      bf16x8 a_xh = *reinterpret_cast<const bf16x8*>(xhi + abase + kf * 32);
      bf16x8 a_xl = *reinterpret_cast<const bf16x8*>(xlo + abase + kf * 32);
      bf16x8 a_hh = *reinterpret_cast<const bf16x8*>(hhi + abase + kf * 32);
      bf16x8 a_hl = *reinterpret_cast<const bf16x8*>(hlo + abase + kf * 32);
#pragma unroll
      for (int g = 0; g < 3; ++g) {
        ax[g] = __builtin_amdgcn_mfma_f32_16x16x32_bf16(a_xh, wfi[g][kf], ax[g], 0, 0, 0);
        ax[g] = __builtin_amdgcn_mfma_f32_16x16x32_bf16(a_xl, wfi[g][kf], ax[g], 0, 0, 0);
        ah[g] = __builtin_amdgcn_mfma_f32_16x16x32_bf16(a_hh, wfh[g][kf], ah[g], 0, 0, 0);
        ah[g] = __builtin_amdgcn_mfma_f32_16x16x32_bf16(a_hl, wfh[g][kf], ah[g], 0, 0, 0);
      }
    }
#pragma unroll
    for (int v = 0; v < 4; ++v) {
      int row = r0 + kg * 4 + v;
      float hp = b2f(hhi[row * 128 + u]) + b2f(hlo[row * 128 + u]);
      float r = sigm(ax[0][v] + ah[0][v] + br_i + br_h);
      float z = sigm(ax[1][v] + ah[1][v] + bz_i + bz_h);
      float n = tanhf(ax[2][v] + bn_i + r * (ah[2][v] + bn_h));
      float hn = (1.f - z) * n + z * hp;
      u16 hb = f2b(hn);
      ohi[row * 128 + u] = hb;
      olo[row * 128 + u] = f2b(hn - b2f(hb));
    }
  }
}

// ---------------------------------------------------------------------------
// MFMA linear (128->128), split-A, optional ReLU, split-bf16 output.
// ---------------------------------------------------------------------------
template <int RELU>
__global__ __launch_bounds__(256) void linear_mfma(
    const u16* __restrict__ xhi, const u16* __restrict__ xlo,
    u16* __restrict__ ohi, u16* __restrict__ olo,
    const u16* __restrict__ W,  // [128][128] bf16
    const float* __restrict__ bias) {
  const int lane = threadIdx.x & 63;
  const int wv = threadIdx.x >> 6;
  const int col = lane & 15;
  const int kg = lane >> 4;
  const int u = blockIdx.y * 64 + wv * 16 + col;
  const int r0b = blockIdx.x * 64;

  bf16x8 wf[4];
#pragma unroll
  for (int kf = 0; kf < 4; ++kf)
    wf[kf] = *reinterpret_cast<const bf16x8*>(W + u * 128 + kf * 32 + kg * 8);
  const float bv = bias[u];
  const f32x4 zz = {0.f, 0.f, 0.f, 0.f};

#pragma unroll
  for (int mt = 0; mt < 4; ++mt) {
    const int r0 = r0b + mt * 16;
    const int abase = (r0 + col) * 128 + kg * 8;
    f32x4 acc = zz;
#pragma unroll
    for (int kf = 0; kf < 4; ++kf) {
      bf16x8 a_h = *reinterpret_cast<const bf16x8*>(xhi + abase + kf * 32);
      bf16x8 a_l = *reinterpret_cast<const bf16x8*>(xlo + abase + kf * 32);
      acc = __builtin_amdgcn_mfma_f32_16x16x32_bf16(a_h, wf[kf], acc, 0, 0, 0);
      acc = __builtin_amdgcn_mfma_f32_16x16x32_bf16(a_l, wf[kf], acc, 0, 0, 0);
    }
#pragma unroll
    for (int v = 0; v < 4; ++v) {
      int row = r0 + kg * 4 + v;
      float val = acc[v] + bv;
      if (RELU) val = val > 0.f ? val : 0.f;
      u16 hb = f2b(val);
      ohi[row * 128 + u] = hb;
      olo[row * 128 + u] = f2b(val - b2f(hb));
    }
  }
}

// ---------------------------------------------------------------------------
// y = (hhi+hlo) @ Wout^T + bout -> out[b, t, 0:2]. 4 lanes per row.
// ---------------------------------------------------------------------------
__global__ __launch_bounds__(256) void y_kernel(
    const u16* __restrict__ hhi, const u16* __restrict__ hlo,
    const float* __restrict__ Wout, const float* __restrict__ bout,
    float* __restrict__ out, int t) {
  const int tid = threadIdx.x;
  const int q = tid & 3, r4 = tid >> 2;
  const int b = blockIdx.x * 64 + r4;
  float s0 = 0.f, s1 = 0.f;
  const int k0 = q * 32;
#pragma unroll
  for (int c8 = 0; c8 < 4; ++c8) {
    int k = k0 + c8 * 8;
    bf16x8 vh = *reinterpret_cast<const bf16x8*>(hhi + b * 128 + k);
    bf16x8 vl = *reinterpret_cast<const bf16x8*>(hlo + b * 128 + k);
#pragma unroll
    for (int j = 0; j < 8; ++j) {
      float hv = b2f((u16)vh[j]) + b2f((u16)vl[j]);
      s0 += hv * Wout[k + j];
      s1 += hv * Wout[128 + k + j];
    }
  }
  s0 += __shfl_xor(s0, 1); s0 += __shfl_xor(s0, 2);
  s1 += __shfl_xor(s1, 1); s1 += __shfl_xor(s1, 2);
  if (q == 0) {
    float2 v;
    v.x = s0 + bout[0];
    v.y = s1 + bout[1];
    *reinterpret_cast<float2*>(&out[b * (TT * 2) + t * 2]) = v;
  }
}

// ---------------------------------------------------------------------------
extern "C" void kernel_launch(void* const* d_in, const int* in_sizes, int n_in,
                              void* d_out, int out_size, void* d_ws, size_t ws_size,
                              hipStream_t stream) {
  const float* x_true   = (const float*)d_in[0];
  const float* enc_Wemb = (const float*)d_in[1];
  const float* enc_bemb = (const float*)d_in[2];
  const float* enc_Wih  = (const float*)d_in[3];
  const float* enc_Whh  = (const float*)d_in[4];
  const float* enc_bih  = (const float*)d_in[5];
  const float* enc_bhh  = (const float*)d_in[6];
  const float* enc_Wt   = (const float*)d_in[7];
  const float* enc_bt   = (const float*)d_in[8];
  const float* dec_Win  = (const float*)d_in[9];
  const float* dec_bin  = (const float*)d_in[10];
  const float* dec_Wih  = (const float*)d_in[11];
  const float* dec_Whh  = (const float*)d_in[12];
  const float* dec_bih  = (const float*)d_in[13];
  const float* dec_bhh  = (const float*)d_in[14];
  const float* dec_Wout = (const float*)d_in[15];
  const float* dec_bout = (const float*)d_in[16];
  float* out = (float*)d_out;

  // ---- bf16 weight arena at start of ws ----
  u16* wsB = (u16*)d_ws;
  const int WC = G3 * HD;               // 49152 per matrix per layer
  u16* encWiB = wsB;                    // 3*WC
  u16* encWhB = encWiB + 3 * WC;
  u16* decWiB = encWhB + 3 * WC;
  u16* decWhB = decWiB + 3 * WC;
  u16* eWtB   = decWhB + 3 * WC;        // 16384
  u16* dWinB  = eWtB + HD * HD;         // 16384
  const size_t arena_u16 = 655360;      // 1.31 MB, aligned pad
  u16* actBase = wsB + arena_u16;

  cvt_kernel<<<(3 * WC + 255) / 256, 256, 0, stream>>>(enc_Wih, encWiB, 3 * WC);
  cvt_kernel<<<(3 * WC + 255) / 256, 256, 0, stream>>>(enc_Whh, encWhB, 3 * WC);
  cvt_kernel<<<(3 * WC + 255) / 256, 256, 0, stream>>>(dec_Wih, decWiB, 3 * WC);
  cvt_kernel<<<(3 * WC + 255) / 256, 256, 0, stream>>>(dec_Whh, decWhB, 3 * WC);
  cvt_kernel<<<(HD * HD + 255) / 256, 256, 0, stream>>>(enc_Wt, eWtB, HD * HD);
  cvt_kernel<<<(HD * HD + 255) / 256, 256, 0, stream>>>(dec_Win, dWinB, HD * HD);

  // ---- adaptive batch chunking: 12 activation arrays of BC*128 u16 ----
  size_t avail = ws_size > arena_u16 * 2 ? ws_size - arena_u16 * 2 : 0;
  const size_t per_row = 12 * HD * sizeof(u16);  // 3072 B
  int BC = 65536, NCH = 1;
  while (BC > 8192 && (size_t)BC * per_row > avail) { BC >>= 1; NCH <<= 1; }

  const size_t L = (size_t)BC * HD;
  u16* Shi[4], *Slo[4];
  for (int s = 0; s < 4; ++s) { Shi[s] = actBase + s * L; Slo[s] = actBase + (4 + s) * L; }
  u16* Xhi = actBase + 8 * L;
  u16* Xlo = actBase + 9 * L;
  u16* Rhi = actBase + 10 * L;
  u16* Rlo = actBase + 11 * L;

  dim3 blk(256);
  dim3 gc(BC / 64, 2);
  dim3 ge(BC / 16);
  dim3 gy(BC / 64);

  for (int c = 0; c < NCH; ++c) {
    const float* xt_c = x_true + (size_t)c * BC * TT * 2;
    float* out_c = out + (size_t)c * BC * TT * 2;

    // ---------------- Encoder ----------------
    hipMemsetAsync(Shi[0], 0, 3 * L * sizeof(u16), stream);
    hipMemsetAsync(Slo[0], 0, 3 * L * sizeof(u16), stream);
    int slot[3] = {0, 1, 2};
    int fre = 3;
    for (int t = 1; t <= TT - 2; ++t) {
      embed_kernel<<<ge, blk, 0, stream>>>(xt_c, enc_Wemb, enc_bemb, Xhi, Xlo, t);
      const u16* inH = Xhi; const u16* inL = Xlo;
      for (int l = 0; l < LL; ++l) {
        gru_cell_mfma<<<gc, blk, 0, stream>>>(
            inH, inL, Shi[slot[l]], Slo[slot[l]], Shi[fre], Slo[fre],
            encWiB + l * WC, encWhB + l * WC,
            enc_bih + l * G3, enc_bhh + l * G3);
        int old = slot[l]; slot[l] = fre; fre = old;
        inH = Shi[slot[l]]; inL = Slo[slot[l]];
      }
    }
    linear_mfma<0><<<gc, blk, 0, stream>>>(Shi[slot[2]], Slo[slot[2]], Rhi, Rlo,
                                           eWtB, enc_bt);

    // ---------------- Decoder ----------------
    hipMemsetAsync(Shi[0], 0, 3 * L * sizeof(u16), stream);
    hipMemsetAsync(Slo[0], 0, 3 * L * sizeof(u16), stream);
    slot[0] = 0; slot[1] = 1; slot[2] = 2; fre = 3;
    const u16* carH = Rhi; const u16* carL = Rlo;
    for (int s = 0; s < TT; ++s) {
      linear_mfma<1><<<gc, blk, 0, stream>>>(carH, carL, Xhi, Xlo, dWinB, dec_bin);
      const u16* inH = Xhi; const u16* inL = Xlo;
      for (int l = 0; l < LL; ++l) {
        gru_cell_mfma<<<gc, blk, 0, stream>>>(
            inH, inL, Shi[slot[l]], Slo[slot[l]], Shi[fre], Slo[fre],
            decWiB + l * WC, decWhB + l * WC,
            dec_bih + l * G3, dec_bhh + l * G3);
        int old = slot[l]; slot[l] = fre; fre = old;
        inH = Shi[slot[l]]; inL = Slo[slot[l]];
      }
      y_kernel<<<gy, blk, 0, stream>>>(Shi[slot[2]], Slo[slot[2]], dec_Wout, dec_bout,
                                       out_c, s);
      carH = Shi[slot[2]]; carL = Slo[slot[2]];
    }
  }
}

// Round 4
// 6025.846 us; speedup vs baseline: 4.1258x; 1.1174x over previous
//
#include <hip/hip_runtime.h>
#include <hip/hip_bf16.h>

#define TT 12
#define HD 128
#define G3 384
#define LL 3
#define BC 32768            // rows per chunk
#define RW 128              // rows per workgroup
#define NWG (BC / RW)       // 256 workgroups
#define NCH 2               // chunks

typedef short bf16x8 __attribute__((ext_vector_type(8)));
typedef float f32x4 __attribute__((ext_vector_type(4)));
typedef unsigned short u16;

__device__ __forceinline__ float b2f(u16 u) {
  union { unsigned int i; float f; } c; c.i = ((unsigned int)u) << 16; return c.f;
}
__device__ __forceinline__ u16 f2b(float f) {
  __hip_bfloat16 h = __float2bfloat16(f);
  union { __hip_bfloat16 h; u16 u; } c; c.h = h; return c.u;
}
__device__ __forceinline__ float fsigm(float x) { return 1.f / (1.f + __expf(-x)); }
__device__ __forceinline__ float ftanh(float x) { return 1.f - 2.f / (__expf(2.f * x) + 1.f); }

// ---------------------------------------------------------------------------
__global__ __launch_bounds__(256) void cvt_kernel(const float* __restrict__ s,
                                                  u16* __restrict__ d, int n) {
  int i = blockIdx.x * 256 + threadIdx.x;
  if (i < n) d[i] = f2b(s[i]);
}

// ---------------------------------------------------------------------------
// GRU cell, one wave = 16 units (u = wv*16+col), 8 M-tiles of 16 rows.
// r,z gates accumulate x-side and h-side into one C each; n keeps nx/nh split.
// ---------------------------------------------------------------------------
__device__ __forceinline__ void gru_cell(
    int r0b, int wv, int lane,
    const u16* __restrict__ inH, const u16* __restrict__ inL,
    const u16* __restrict__ hoH, const u16* __restrict__ hoL,
    u16* __restrict__ nwH, u16* __restrict__ nwL,
    const u16* __restrict__ Wi, const u16* __restrict__ Wh,
    const float* __restrict__ bih, const float* __restrict__ bhh) {
  const int col = lane & 15, kg = lane >> 4;
  const int u = wv * 16 + col;

  bf16x8 wfi[3][4], wfh[3][4];
#pragma unroll
  for (int g = 0; g < 3; ++g)
#pragma unroll
    for (int kf = 0; kf < 4; ++kf) {
      int off = (g * 128 + u) * 128 + kf * 32 + kg * 8;
      wfi[g][kf] = *reinterpret_cast<const bf16x8*>(Wi + off);
      wfh[g][kf] = *reinterpret_cast<const bf16x8*>(Wh + off);
    }
  const float br = bih[u] + bhh[u];
  const float bz = bih[128 + u] + bhh[128 + u];
  const float bni = bih[256 + u], bnh = bhh[256 + u];
  const f32x4 zz = {0.f, 0.f, 0.f, 0.f};

#pragma unroll
  for (int mt = 0; mt < RW / 16; ++mt) {
    const int r0 = r0b + mt * 16;
    const int abase = (r0 + col) * 128 + kg * 8;
    f32x4 ar = zz, az = zz, anx = zz, anh = zz;
#pragma unroll
    for (int kf = 0; kf < 4; ++kf) {
      bf16x8 a_xh = *reinterpret_cast<const bf16x8*>(inH + abase + kf * 32);
      bf16x8 a_xl = *reinterpret_cast<const bf16x8*>(inL + abase + kf * 32);
      bf16x8 a_hh = *reinterpret_cast<const bf16x8*>(hoH + abase + kf * 32);
      bf16x8 a_hl = *reinterpret_cast<const bf16x8*>(hoL + abase + kf * 32);
      ar = __builtin_amdgcn_mfma_f32_16x16x32_bf16(a_xh, wfi[0][kf], ar, 0, 0, 0);
      ar = __builtin_amdgcn_mfma_f32_16x16x32_bf16(a_xl, wfi[0][kf], ar, 0, 0, 0);
      ar = __builtin_amdgcn_mfma_f32_16x16x32_bf16(a_hh, wfh[0][kf], ar, 0, 0, 0);
      ar = __builtin_amdgcn_mfma_f32_16x16x32_bf16(a_hl, wfh[0][kf], ar, 0, 0, 0);
      az = __builtin_amdgcn_mfma_f32_16x16x32_bf16(a_xh, wfi[1][kf], az, 0, 0, 0);
      az = __builtin_amdgcn_mfma_f32_16x16x32_bf16(a_xl, wfi[1][kf], az, 0, 0, 0);
      az = __builtin_amdgcn_mfma_f32_16x16x32_bf16(a_hh, wfh[1][kf], az, 0, 0, 0);
      az = __builtin_amdgcn_mfma_f32_16x16x32_bf16(a_hl, wfh[1][kf], az, 0, 0, 0);
      anx = __builtin_amdgcn_mfma_f32_16x16x32_bf16(a_xh, wfi[2][kf], anx, 0, 0, 0);
      anx = __builtin_amdgcn_mfma_f32_16x16x32_bf16(a_xl, wfi[2][kf], anx, 0, 0, 0);
      anh = __builtin_amdgcn_mfma_f32_16x16x32_bf16(a_hh, wfh[2][kf], anh, 0, 0, 0);
      anh = __builtin_amdgcn_mfma_f32_16x16x32_bf16(a_hl, wfh[2][kf], anh, 0, 0, 0);
    }
#pragma unroll
    for (int v = 0; v < 4; ++v) {
      int row = r0 + kg * 4 + v;
      int idx = row * 128 + u;
      float hp = b2f(hoH[idx]) + b2f(hoL[idx]);
      float rg = fsigm(ar[v] + br);
      float zg = fsigm(az[v] + bz);
      float ng = ftanh(anx[v] + bni + rg * (anh[v] + bnh));
      float hn = (1.f - zg) * ng + zg * hp;
      u16 hb = f2b(hn);
      nwH[idx] = hb;
      nwL[idx] = f2b(hn - b2f(hb));
    }
  }
}

// ---------------------------------------------------------------------------
template <int RELU>
__device__ __forceinline__ void lin128(
    int r0b, int wv, int lane,
    const u16* __restrict__ inH, const u16* __restrict__ inL,
    u16* __restrict__ oH, u16* __restrict__ oL,
    const u16* __restrict__ W, const float* __restrict__ bias) {
  const int col = lane & 15, kg = lane >> 4;
  const int u = wv * 16 + col;
  bf16x8 wf[4];
#pragma unroll
  for (int kf = 0; kf < 4; ++kf)
    wf[kf] = *reinterpret_cast<const bf16x8*>(W + u * 128 + kf * 32 + kg * 8);
  const float bv = bias[u];
  const f32x4 zz = {0.f, 0.f, 0.f, 0.f};
#pragma unroll
  for (int mt = 0; mt < RW / 16; ++mt) {
    const int r0 = r0b + mt * 16;
    const int abase = (r0 + col) * 128 + kg * 8;
    f32x4 acc = zz;
#pragma unroll
    for (int kf = 0; kf < 4; ++kf) {
      bf16x8 ah = *reinterpret_cast<const bf16x8*>(inH + abase + kf * 32);
      bf16x8 al = *reinterpret_cast<const bf16x8*>(inL + abase + kf * 32);
      acc = __builtin_amdgcn_mfma_f32_16x16x32_bf16(ah, wf[kf], acc, 0, 0, 0);
      acc = __builtin_amdgcn_mfma_f32_16x16x32_bf16(al, wf[kf], acc, 0, 0, 0);
    }
#pragma unroll
    for (int v = 0; v < 4; ++v) {
      int row = r0 + kg * 4 + v;
      float val = acc[v] + bv;
      if (RELU) val = val > 0.f ? val : 0.f;
      u16 hb = f2b(val);
      oH[row * 128 + u] = hb;
      oL[row * 128 + u] = f2b(val - b2f(hb));
    }
  }
}

// ---------------------------------------------------------------------------
// The mega-kernel: one workgroup owns RW rows for the entire enc+dec pass.
// ---------------------------------------------------------------------------
__global__ __launch_bounds__(512, 2) void mega_kernel(
    const float* __restrict__ x_true, float* __restrict__ out,
    const u16* __restrict__ eWi, const u16* __restrict__ eWh,
    const float* __restrict__ ebi, const float* __restrict__ ebh,
    const u16* __restrict__ eWt, const float* __restrict__ ebt,
    const u16* __restrict__ dWin, const float* __restrict__ dbin,
    const u16* __restrict__ dWi, const u16* __restrict__ dWh,
    const float* __restrict__ dbi, const float* __restrict__ dbh,
    const float* __restrict__ Wemb, const float* __restrict__ bemb,
    const float* __restrict__ Wout, const float* __restrict__ bout,
    u16* Xh, u16* Xl, u16* Rh, u16* Rl, u16* Hh, u16* Hl) {
  __shared__ float sWe0[128], sWe1[128], sBe[128], sW0[128], sW1[128], sBo[2];
  const int tid = threadIdx.x;
  const int wv = tid >> 6, lane = tid & 63;
  const int r0b = blockIdx.x * RW;
  const size_t HS = (size_t)BC * 128;   // per (layer,slot) array elems

  if (tid < 128) {
    sWe0[tid] = Wemb[2 * tid]; sWe1[tid] = Wemb[2 * tid + 1]; sBe[tid] = bemb[tid];
    sW0[tid] = Wout[tid]; sW1[tid] = Wout[128 + tid];
  }
  if (tid == 128) { sBo[0] = bout[0]; sBo[1] = bout[1]; }

  // zero slot-0 h for own rows (3 layers, hi+lo)
  const bf16x8 z8 = {0, 0, 0, 0, 0, 0, 0, 0};
#pragma unroll
  for (int l = 0; l < LL; ++l) {
    size_t base = (size_t)(l * 2) * HS + (size_t)r0b * 128 + tid * 32;
#pragma unroll
    for (int j = 0; j < 4; ++j) {
      *reinterpret_cast<bf16x8*>(Hh + base + j * 8) = z8;
      *reinterpret_cast<bf16x8*>(Hl + base + j * 8) = z8;
    }
  }
  __syncthreads();

  int sl[3] = {0, 0, 0};

  // ---------------- Encoder ----------------
#pragma unroll 1
  for (int t = 1; t <= TT - 2; ++t) {
    {  // inline embed: thread -> row tid>>2, elems (tid&3)*32..+31
      int r = tid >> 2, e0 = (tid & 3) * 32;
      int grow = r0b + r;
      float x0 = x_true[(grow * TT + t) * 2];
      float x1 = x_true[(grow * TT + t) * 2 + 1];
#pragma unroll
      for (int j8 = 0; j8 < 4; ++j8) {
        bf16x8 vh, vl;
#pragma unroll
        for (int j = 0; j < 8; ++j) {
          int e = e0 + j8 * 8 + j;
          float v = x0 * sWe0[e] + x1 * sWe1[e] + sBe[e];
          v = v > 0.f ? v : 0.f;
          u16 hb = f2b(v);
          vh[j] = (short)hb;
          vl[j] = (short)f2b(v - b2f(hb));
        }
        *reinterpret_cast<bf16x8*>(Xh + grow * 128 + e0 + j8 * 8) = vh;
        *reinterpret_cast<bf16x8*>(Xl + grow * 128 + e0 + j8 * 8) = vl;
      }
    }
    __syncthreads();
    const u16* inH = Xh; const u16* inL = Xl;
#pragma unroll 1
    for (int l = 0; l < LL; ++l) {
      const u16* hoH = Hh + (size_t)(l * 2 + sl[l]) * HS;
      const u16* hoL = Hl + (size_t)(l * 2 + sl[l]) * HS;
      u16* nwH = Hh + (size_t)(l * 2 + 1 - sl[l]) * HS;
      u16* nwL = Hl + (size_t)(l * 2 + 1 - sl[l]) * HS;
      gru_cell(r0b, wv, lane, inH, inL, hoH, hoL, nwH, nwL,
               eWi + (size_t)l * G3 * HD, eWh + (size_t)l * G3 * HD,
               ebi + l * G3, ebh + l * G3);
      sl[l] ^= 1;
      inH = nwH; inL = nwL;
      __syncthreads();
    }
  }
  // rep = htop @ Wt^T + bt
  lin128<0>(r0b, wv, lane, Hh + (size_t)(4 + sl[2]) * HS, Hl + (size_t)(4 + sl[2]) * HS,
            Rh, Rl, eWt, ebt);
  __syncthreads();
  // zero slot-0 h for decoder
#pragma unroll
  for (int l = 0; l < LL; ++l) {
    size_t base = (size_t)(l * 2) * HS + (size_t)r0b * 128 + tid * 32;
#pragma unroll
    for (int j = 0; j < 4; ++j) {
      *reinterpret_cast<bf16x8*>(Hh + base + j * 8) = z8;
      *reinterpret_cast<bf16x8*>(Hl + base + j * 8) = z8;
    }
  }
  sl[0] = sl[1] = sl[2] = 0;
  __syncthreads();

  // ---------------- Decoder ----------------
  const u16* caH = Rh; const u16* caL = Rl;
#pragma unroll 1
  for (int s = 0; s < TT; ++s) {
    lin128<1>(r0b, wv, lane, caH, caL, Xh, Xl, dWin, dbin);
    __syncthreads();
    const u16* inH = Xh; const u16* inL = Xl;
#pragma unroll 1
    for (int l = 0; l < LL; ++l) {
      const u16* hoH = Hh + (size_t)(l * 2 + sl[l]) * HS;
      const u16* hoL = Hl + (size_t)(l * 2 + sl[l]) * HS;
      u16* nwH = Hh + (size_t)(l * 2 + 1 - sl[l]) * HS;
      u16* nwL = Hl + (size_t)(l * 2 + 1 - sl[l]) * HS;
      gru_cell(r0b, wv, lane, inH, inL, hoH, hoL, nwH, nwL,
               dWi + (size_t)l * G3 * HD, dWh + (size_t)l * G3 * HD,
               dbi + l * G3, dbh + l * G3);
      sl[l] ^= 1;
      inH = nwH; inL = nwL;
      __syncthreads();
    }
    const u16* thH = Hh + (size_t)(4 + sl[2]) * HS;
    const u16* thL = Hl + (size_t)(4 + sl[2]) * HS;
    // y projection: 8 threads per row, 2 halves of 64 rows
#pragma unroll
    for (int half = 0; half < 2; ++half) {
      int r = half * 64 + (tid >> 3), kc = tid & 7;
      int grow = r0b + r;
      int k0 = kc * 16;
      float s0 = 0.f, s1 = 0.f;
#pragma unroll
      for (int c8 = 0; c8 < 2; ++c8) {
        bf16x8 vh = *reinterpret_cast<const bf16x8*>(thH + grow * 128 + k0 + c8 * 8);
        bf16x8 vl = *reinterpret_cast<const bf16x8*>(thL + grow * 128 + k0 + c8 * 8);
#pragma unroll
        for (int j = 0; j < 8; ++j) {
          float hv = b2f((u16)vh[j]) + b2f((u16)vl[j]);
          s0 += hv * sW0[k0 + c8 * 8 + j];
          s1 += hv * sW1[k0 + c8 * 8 + j];
        }
      }
      s0 += __shfl_xor(s0, 1); s0 += __shfl_xor(s0, 2); s0 += __shfl_xor(s0, 4);
      s1 += __shfl_xor(s1, 1); s1 += __shfl_xor(s1, 2); s1 += __shfl_xor(s1, 4);
      if (kc == 0) {
        float2 y; y.x = s0 + sBo[0]; y.y = s1 + sBo[1];
        *reinterpret_cast<float2*>(&out[(grow * TT + s) * 2]) = y;
      }
    }
    caH = thH; caL = thL;
    __syncthreads();
  }
}

// ---------------------------------------------------------------------------
extern "C" void kernel_launch(void* const* d_in, const int* in_sizes, int n_in,
                              void* d_out, int out_size, void* d_ws, size_t ws_size,
                              hipStream_t stream) {
  const float* x_true   = (const float*)d_in[0];
  const float* enc_Wemb = (const float*)d_in[1];
  const float* enc_bemb = (const float*)d_in[2];
  const float* enc_Wih  = (const float*)d_in[3];
  const float* enc_Whh  = (const float*)d_in[4];
  const float* enc_bih  = (const float*)d_in[5];
  const float* enc_bhh  = (const float*)d_in[6];
  const float* enc_Wt   = (const float*)d_in[7];
  const float* enc_bt   = (const float*)d_in[8];
  const float* dec_Win  = (const float*)d_in[9];
  const float* dec_bin  = (const float*)d_in[10];
  const float* dec_Wih  = (const float*)d_in[11];
  const float* dec_Whh  = (const float*)d_in[12];
  const float* dec_bih  = (const float*)d_in[13];
  const float* dec_bhh  = (const float*)d_in[14];
  const float* dec_Wout = (const float*)d_in[15];
  const float* dec_bout = (const float*)d_in[16];
  float* out = (float*)d_out;

  // ---- bf16 weight arena ----
  u16* wsB = (u16*)d_ws;
  const int WC = G3 * HD;
  u16* encWiB = wsB;
  u16* encWhB = encWiB + 3 * WC;
  u16* decWiB = encWhB + 3 * WC;
  u16* decWhB = decWiB + 3 * WC;
  u16* eWtB   = decWhB + 3 * WC;
  u16* dWinB  = eWtB + HD * HD;
  const size_t arena_u16 = 655360;
  u16* actBase = wsB + arena_u16;

  cvt_kernel<<<(3 * WC + 255) / 256, 256, 0, stream>>>(enc_Wih, encWiB, 3 * WC);
  cvt_kernel<<<(3 * WC + 255) / 256, 256, 0, stream>>>(enc_Whh, encWhB, 3 * WC);
  cvt_kernel<<<(3 * WC + 255) / 256, 256, 0, stream>>>(dec_Wih, decWiB, 3 * WC);
  cvt_kernel<<<(3 * WC + 255) / 256, 256, 0, stream>>>(dec_Whh, decWhB, 3 * WC);
  cvt_kernel<<<(HD * HD + 255) / 256, 256, 0, stream>>>(enc_Wt, eWtB, HD * HD);
  cvt_kernel<<<(HD * HD + 255) / 256, 256, 0, stream>>>(dec_Win, dWinB, HD * HD);

  // ---- activation arrays: 16 x (BC*128) u16 = 134 MB ----
  const size_t L = (size_t)BC * 128;
  u16* Xh = actBase;
  u16* Xl = Xh + L;
  u16* Rh = Xl + L;
  u16* Rl = Rh + L;
  u16* Hh = Rl + L;          // [3][2] arrays
  u16* Hl = Hh + 6 * L;      // [3][2] arrays

  for (int c = 0; c < NCH; ++c) {
    mega_kernel<<<NWG, 512, 0, stream>>>(
        x_true + (size_t)c * BC * TT * 2, out + (size_t)c * BC * TT * 2,
        encWiB, encWhB, enc_bih, enc_bhh, eWtB, enc_bt,
        dWinB, dec_bin, decWiB, decWhB, dec_bih, dec_bhh,
        enc_Wemb, enc_bemb, dec_Wout, dec_bout,
        Xh, Xl, Rh, Rl, Hh, Hl);
  }
}